// Round 1
// baseline (793.036 us; speedup 1.0000x reference)
//
#include <hip/hip_runtime.h>
#include <hip/hip_bf16.h>
#include <cstdint>
#include <cstddef>

#define N_NODES 32768
#define N_EDGES 262144
#define BGRAPH  32
#define NPG     1024
#define KSEL    820
#define NEG     0.2f

// ---------------------------------------------------------------------------
// GEMM: xl = x@Wl + bl (cols 0..511 logical) ; xr = x@Wr + br (cols 512..1023)
// A = x [32768 x 256] row-major, W [256 x 512] row-major each.
// 128x128x16 tile, 256 threads, 8x8 micro-tile, fp32 VALU.
// ---------------------------------------------------------------------------
#define BM 128
#define BN 128
#define BK 16

__global__ __launch_bounds__(256) void gemm_xlxr(
    const float* __restrict__ x,
    const float* __restrict__ Wl, const float* __restrict__ bl,
    const float* __restrict__ Wr, const float* __restrict__ br,
    float* __restrict__ xl, float* __restrict__ xr)
{
    __shared__ float As[BK][BM];
    __shared__ float Bs[BK][BN];

    const int bm = blockIdx.x;      // 0..255
    const int bn = blockIdx.y;      // 0..7
    const float* W; const float* bias; float* out; int colbase;
    if (bn < 4) { W = Wl; bias = bl; out = xl; colbase = bn * 128; }
    else        { W = Wr; bias = br; out = xr; colbase = (bn - 4) * 128; }

    const int tid = threadIdx.x;
    const int tm = tid >> 4;        // 0..15
    const int tn = tid & 15;        // 0..15

    float acc[8][8];
#pragma unroll
    for (int i = 0; i < 8; ++i)
#pragma unroll
        for (int j = 0; j < 8; ++j) acc[i][j] = 0.f;

    for (int k0 = 0; k0 < 256; k0 += BK) {
        __syncthreads();
        // stage A: 128 rows x 16 k = 512 float4, 2 per thread; As[k][m]
#pragma unroll
        for (int p = 0; p < 2; ++p) {
            int id  = tid + p * 256;
            int row = id >> 2;
            int kc  = (id & 3) << 2;
            float4 v = *(const float4*)&x[(size_t)(bm * BM + row) * 256 + k0 + kc];
            As[kc + 0][row] = v.x; As[kc + 1][row] = v.y;
            As[kc + 2][row] = v.z; As[kc + 3][row] = v.w;
        }
        // stage B: 16 k x 128 n = 512 float4, 2 per thread; Bs[k][n]
#pragma unroll
        for (int p = 0; p < 2; ++p) {
            int id = tid + p * 256;
            int kk = id >> 5;
            int nf = (id & 31) << 2;
            float4 v = *(const float4*)&W[(size_t)(k0 + kk) * 512 + colbase + nf];
            *(float4*)&Bs[kk][nf] = v;
        }
        __syncthreads();
#pragma unroll
        for (int kk = 0; kk < BK; ++kk) {
            float a[8], b[8];
            *(float4*)&a[0] = *(const float4*)&As[kk][tm * 8];
            *(float4*)&a[4] = *(const float4*)&As[kk][tm * 8 + 4];
            *(float4*)&b[0] = *(const float4*)&Bs[kk][tn * 8];
            *(float4*)&b[4] = *(const float4*)&Bs[kk][tn * 8 + 4];
#pragma unroll
            for (int i = 0; i < 8; ++i)
#pragma unroll
                for (int j = 0; j < 8; ++j) acc[i][j] += a[i] * b[j];
        }
    }

    float bv[8];
    *(float4*)&bv[0] = *(const float4*)&bias[colbase + tn * 8];
    *(float4*)&bv[4] = *(const float4*)&bias[colbase + tn * 8 + 4];
#pragma unroll
    for (int i = 0; i < 8; ++i) {
        int row = bm * BM + tm * 8 + i;
        float4 o0 = make_float4(acc[i][0] + bv[0], acc[i][1] + bv[1],
                                acc[i][2] + bv[2], acc[i][3] + bv[3]);
        float4 o1 = make_float4(acc[i][4] + bv[4], acc[i][5] + bv[5],
                                acc[i][6] + bv[6], acc[i][7] + bv[7]);
        *(float4*)&out[(size_t)row * 512 + colbase + tn * 8]     = o0;
        *(float4*)&out[(size_t)row * 512 + colbase + tn * 8 + 4] = o1;
    }
}

// ---------------------------------------------------------------------------
// Counting sort of edges by dst
// ---------------------------------------------------------------------------
__global__ void k_hist(const int* __restrict__ ei, int* __restrict__ counts)
{
    int e = blockIdx.x * 256 + threadIdx.x;
    if (e < N_EDGES) atomicAdd(&counts[ei[N_EDGES + e]], 1);
}

__global__ __launch_bounds__(1024) void k_scan(
    const int* __restrict__ counts, int* __restrict__ offsets, int* __restrict__ cursors)
{
    __shared__ int part[1024];
    const int tid = threadIdx.x;
    const int base = tid * 32;
    int loc[32];
    int s = 0;
#pragma unroll
    for (int i = 0; i < 32; ++i) { loc[i] = s; s += counts[base + i]; }
    part[tid] = s;
    __syncthreads();
    const int own = s;
    for (int off = 1; off < 1024; off <<= 1) {
        int v = (tid >= off) ? part[tid - off] : 0;
        __syncthreads();
        part[tid] += v;
        __syncthreads();
    }
    const int pre = part[tid] - own;   // exclusive prefix of chunk
#pragma unroll
    for (int i = 0; i < 32; ++i) {
        int o = pre + loc[i];
        offsets[base + i] = o;
        cursors[base + i] = o;
    }
}

__global__ void k_scatter(const int* __restrict__ ei, int* __restrict__ cursors,
                          int* __restrict__ sorted_src, int* __restrict__ sorted_eid)
{
    int e = blockIdx.x * 256 + threadIdx.x;
    if (e >= N_EDGES) return;
    int d = ei[N_EDGES + e];
    int pos = atomicAdd(&cursors[d], 1);
    sorted_src[pos] = ei[e];
    sorted_eid[pos] = e;
}

__global__ void k_gather_ea(const int* __restrict__ sorted_eid,
                            const float* __restrict__ ea, float* __restrict__ sorted_ea)
{
    // 256 threads = 8 edges x 32 cols
    int pos = blockIdx.x * 8 + (threadIdx.x >> 5);
    int col = threadIdx.x & 31;
    int e = sorted_eid[pos];
    sorted_ea[(size_t)pos * 32 + col] = ea[(size_t)e * 32 + col];
}

// ---------------------------------------------------------------------------
// Fused edge kernel: per-dst, compute per-edge alpha (We-dot + gather + lrelu
// + att-dot + wave reduce), online-softmax, weighted aggregate of xl[src],
// then h = relu(out + bias), write h, score = tanh(h.pw / ||pw||).
// One workgroup handles DPW consecutive dst nodes; 256 threads own 2 channels
// each (c, c+256) so wave w reduces exactly heads (w, w+4).
// ---------------------------------------------------------------------------
#define DPW   16
#define CHUNK 8

__global__ __launch_bounds__(256) void k_edge_agg(
    const float* __restrict__ xl, const float* __restrict__ xr,
    const float* __restrict__ We, const float* __restrict__ att,
    const float* __restrict__ bias, const float* __restrict__ pw,
    const float* __restrict__ sorted_ea, const int* __restrict__ sorted_src,
    const int* __restrict__ offsets, const int* __restrict__ counts,
    float* __restrict__ h, float* __restrict__ score)
{
    __shared__ float ea_s[CHUNK * 32];
    __shared__ int   src_s[CHUNK];
    __shared__ float red_s[4];

    const int tid = threadIdx.x;
    const int c0 = tid, c1 = tid + 256;

    float we0[32], we1[32];
#pragma unroll
    for (int k = 0; k < 32; ++k) { we0[k] = We[k * 512 + c0]; we1[k] = We[k * 512 + c1]; }
    const float att0 = att[c0],  att1 = att[c1];
    const float b0   = bias[c0], b1   = bias[c1];
    const float pw0  = pw[c0],   pw1  = pw[c1];

    // ||pool_w|| (block reduce, once)
    float nrm = pw0 * pw0 + pw1 * pw1;
#pragma unroll
    for (int o = 32; o; o >>= 1) nrm += __shfl_xor(nrm, o);
    if ((tid & 63) == 0) red_s[tid >> 6] = nrm;
    __syncthreads();
    const float inv_nrm = 1.0f / sqrtf(red_s[0] + red_s[1] + red_s[2] + red_s[3]);

    for (int dd = 0; dd < DPW; ++dd) {
        const int d   = blockIdx.x * DPW + dd;
        const int off = offsets[d];
        const int deg = counts[d];
        const float xr0 = xr[(size_t)d * 512 + c0];
        const float xr1 = xr[(size_t)d * 512 + c1];

        float m0 = -INFINITY, m1 = -INFINITY;
        float den0 = 0.f, den1 = 0.f, acc0 = 0.f, acc1 = 0.f;

        for (int baseE = 0; baseE < deg; baseE += CHUNK) {
            const int n = min(CHUNK, deg - baseE);
            __syncthreads();
            if (tid < n * 32) ea_s[tid] = sorted_ea[(size_t)(off + baseE) * 32 + tid];
            if (tid < n)      src_s[tid] = sorted_src[off + baseE + tid];
            __syncthreads();
            for (int j = 0; j < n; ++j) {
                const int s = src_s[j];
                const float xl0 = xl[(size_t)s * 512 + c0];
                const float xl1 = xl[(size_t)s * 512 + c1];
                float dot0 = 0.f, dot1 = 0.f;
                const float4* e4 = (const float4*)&ea_s[j * 32];
#pragma unroll
                for (int k = 0; k < 8; ++k) {
                    float4 v = e4[k];
                    dot0 += v.x * we0[4*k] + v.y * we0[4*k+1] + v.z * we0[4*k+2] + v.w * we0[4*k+3];
                    dot1 += v.x * we1[4*k] + v.y * we1[4*k+1] + v.z * we1[4*k+2] + v.w * we1[4*k+3];
                }
                float t0 = xl0 + xr0 + dot0; t0 = t0 > 0.f ? t0 : NEG * t0;
                float t1 = xl1 + xr1 + dot1; t1 = t1 > 0.f ? t1 : NEG * t1;
                float p0 = t0 * att0, p1 = t1 * att1;
#pragma unroll
                for (int o = 32; o; o >>= 1) { p0 += __shfl_xor(p0, o); p1 += __shfl_xor(p1, o); }
                // online softmax (per-wave-uniform running state)
                float mn, sc, pe;
                mn = fmaxf(m0, p0); sc = __expf(m0 - mn); pe = __expf(p0 - mn);
                den0 = den0 * sc + pe; acc0 = acc0 * sc + pe * xl0; m0 = mn;
                mn = fmaxf(m1, p1); sc = __expf(m1 - mn); pe = __expf(p1 - mn);
                den1 = den1 * sc + pe; acc1 = acc1 * sc + pe * xl1; m1 = mn;
            }
        }

        const float o0 = den0 > 0.f ? acc0 / den0 : 0.f;
        const float o1 = den1 > 0.f ? acc1 / den1 : 0.f;
        const float h0 = fmaxf(o0 + b0, 0.f);
        const float h1 = fmaxf(o1 + b1, 0.f);
        h[(size_t)d * 512 + c0] = h0;
        h[(size_t)d * 512 + c1] = h1;

        float ps = h0 * pw0 + h1 * pw1;
#pragma unroll
        for (int o = 32; o; o >>= 1) ps += __shfl_xor(ps, o);
        __syncthreads();                      // protect red_s reuse
        if ((tid & 63) == 0) red_s[tid >> 6] = ps;
        __syncthreads();
        if (tid == 0)
            score[d] = tanhf((red_s[0] + red_s[1] + red_s[2] + red_s[3]) * inv_nrm);
    }
}

// ---------------------------------------------------------------------------
// Per-graph top-K via bitonic sort of packed keys (score desc, idx asc)
// ---------------------------------------------------------------------------
__global__ __launch_bounds__(256) void k_topk(const float* __restrict__ score,
                                              int* __restrict__ sel_idx,
                                              float* __restrict__ sel_val)
{
    __shared__ unsigned long long key[1024];
    const int g = blockIdx.x, tid = threadIdx.x;
    for (int i = tid; i < 1024; i += 256) {
        float s = score[g * 1024 + i];
        unsigned u = __float_as_uint(s);
        u = (u & 0x80000000u) ? ~u : (u | 0x80000000u);   // orderable, ascending
        key[i] = ((unsigned long long)(~u) << 32) | (unsigned)i;  // asc key == desc score
    }
    __syncthreads();
    for (int k = 2; k <= 1024; k <<= 1) {
        for (int j = k >> 1; j > 0; j >>= 1) {
            for (int i = tid; i < 1024; i += 256) {
                int ixj = i ^ j;
                if (ixj > i) {
                    bool up = ((i & k) == 0);
                    unsigned long long a = key[i], b = key[ixj];
                    if ((a > b) == up) { key[i] = b; key[ixj] = a; }
                }
            }
            __syncthreads();
        }
    }
    for (int kk = tid; kk < KSEL; kk += 256) {
        int idx = (int)(key[kk] & 0xFFFFFFFFu);
        sel_idx[g * KSEL + kk] = idx;
        sel_val[g * KSEL + kk] = score[g * 1024 + idx];
    }
}

// ---------------------------------------------------------------------------
// Pool: gmp = max_k(h[idx_k]*val_k), gap = mean_k(...) — k-sliced + merge
// ---------------------------------------------------------------------------
#define KSLICE 103

__global__ __launch_bounds__(256) void k_pool_part(
    const float* __restrict__ h, const int* __restrict__ sel_idx,
    const float* __restrict__ sel_val, float* __restrict__ part)
{
    const int g = blockIdx.x >> 3, sl = blockIdx.x & 7;
    const int kbeg = sl * KSLICE;
    const int kend = min(KSEL, kbeg + KSLICE);
    const int n = kend - kbeg;
    __shared__ float vs[KSLICE];
    __shared__ int   is_[KSLICE];
    const int tid = threadIdx.x;
    if (tid < n) {
        vs[tid]  = sel_val[g * KSEL + kbeg + tid];
        is_[tid] = sel_idx[g * KSEL + kbeg + tid];
    }
    __syncthreads();
    const int c0 = tid, c1 = tid + 256;
    float mx0 = -INFINITY, mx1 = -INFINITY, s0 = 0.f, s1 = 0.f;
    for (int kk = 0; kk < n; ++kk) {
        const float* hp = h + ((size_t)(g * 1024 + is_[kk])) * 512;
        const float v = vs[kk];
        float f0 = hp[c0] * v, f1 = hp[c1] * v;
        mx0 = fmaxf(mx0, f0); s0 += f0;
        mx1 = fmaxf(mx1, f1); s1 += f1;
    }
    const size_t base = ((size_t)blockIdx.x * 2) * 512;
    part[base + c0] = mx0;        part[base + c1] = mx1;
    part[base + 512 + c0] = s0;   part[base + 512 + c1] = s1;
}

__global__ __launch_bounds__(256) void k_pool_merge(
    const float* __restrict__ part, float* __restrict__ out)
{
    const int g = blockIdx.x, tid = threadIdx.x;
    const int c0 = tid, c1 = tid + 256;
    float mx0 = -INFINITY, mx1 = -INFINITY, s0 = 0.f, s1 = 0.f;
    for (int sl = 0; sl < 8; ++sl) {
        const size_t base = ((size_t)(g * 8 + sl) * 2) * 512;
        mx0 = fmaxf(mx0, part[base + c0]); mx1 = fmaxf(mx1, part[base + c1]);
        s0 += part[base + 512 + c0];       s1 += part[base + 512 + c1];
    }
    out[(size_t)g * 1024 + c0] = mx0;
    out[(size_t)g * 1024 + c1] = mx1;
    out[(size_t)g * 1024 + 512 + c0] = s0 * (1.f / KSEL);
    out[(size_t)g * 1024 + 512 + c1] = s1 * (1.f / KSEL);
}

// ---------------------------------------------------------------------------
extern "C" void kernel_launch(void* const* d_in, const int* in_sizes, int n_in,
                              void* d_out, int out_size, void* d_ws, size_t ws_size,
                              hipStream_t stream)
{
    const float* x    = (const float*)d_in[0];
    const float* ea   = (const float*)d_in[1];
    const float* Wl   = (const float*)d_in[2];
    const float* bl   = (const float*)d_in[3];
    const float* Wr   = (const float*)d_in[4];
    const float* br   = (const float*)d_in[5];
    const float* We   = (const float*)d_in[6];
    const float* att  = (const float*)d_in[7];
    const float* bias = (const float*)d_in[8];
    const float* pw   = (const float*)d_in[9];
    const int*   ei   = (const int*)d_in[10];
    float* out = (float*)d_out;

    // workspace layout (floats/ints, 4B each)
    float* xl        = (float*)d_ws;                      // 32768*512
    float* xr        = xl + (size_t)N_NODES * 512;
    float* h         = xr + (size_t)N_NODES * 512;
    float* sorted_ea = h + (size_t)N_NODES * 512;         // E*32
    float* sel_val   = sorted_ea + (size_t)N_EDGES * 32;  // 32*820
    float* part      = sel_val + BGRAPH * KSEL;           // 256*2*512
    float* score     = part + 256 * 2 * 512;              // 32768
    int* counts      = (int*)(score + N_NODES);
    int* offsets     = counts + N_NODES;
    int* cursors     = offsets + N_NODES;
    int* sorted_src  = cursors + N_NODES;                 // E
    int* sorted_eid  = sorted_src + N_EDGES;              // E
    int* sel_idx     = sorted_eid + N_EDGES;              // 32*820

    hipMemsetAsync(counts, 0, (size_t)N_NODES * sizeof(int), stream);

    gemm_xlxr<<<dim3(256, 8), 256, 0, stream>>>(x, Wl, bl, Wr, br, xl, xr);
    k_hist<<<N_EDGES / 256, 256, 0, stream>>>(ei, counts);
    k_scan<<<1, 1024, 0, stream>>>(counts, offsets, cursors);
    k_scatter<<<N_EDGES / 256, 256, 0, stream>>>(ei, cursors, sorted_src, sorted_eid);
    k_gather_ea<<<N_EDGES / 8, 256, 0, stream>>>(sorted_eid, ea, sorted_ea);
    k_edge_agg<<<N_NODES / DPW, 256, 0, stream>>>(xl, xr, We, att, bias, pw,
                                                  sorted_ea, sorted_src, offsets, counts,
                                                  h, score);
    k_topk<<<BGRAPH, 256, 0, stream>>>(score, sel_idx, sel_val);
    k_pool_part<<<BGRAPH * 8, 256, 0, stream>>>(h, sel_idx, sel_val, part);
    k_pool_merge<<<BGRAPH, 256, 0, stream>>>(part, out);
}

// Round 2
// 651.025 us; speedup vs baseline: 1.2181x; 1.2181x over previous
//
#include <hip/hip_runtime.h>
#include <hip/hip_bf16.h>
#include <cstdint>
#include <cstddef>

#define N_NODES 32768
#define N_EDGES 262144
#define BGRAPH  32
#define NPG     1024
#define KSEL    820
#define NEG     0.2f

// ---------------------------------------------------------------------------
// GEMM: xl = x@Wl + bl ; xr = x@Wr + br   (fp32 VALU, unchanged this round)
// ---------------------------------------------------------------------------
#define BM 128
#define BN 128
#define BK 16

__global__ __launch_bounds__(256) void gemm_xlxr(
    const float* __restrict__ x,
    const float* __restrict__ Wl, const float* __restrict__ bl,
    const float* __restrict__ Wr, const float* __restrict__ br,
    float* __restrict__ xl, float* __restrict__ xr)
{
    __shared__ float As[BK][BM];
    __shared__ float Bs[BK][BN];

    const int bm = blockIdx.x;      // 0..255
    const int bn = blockIdx.y;      // 0..7
    const float* W; const float* bias; float* out; int colbase;
    if (bn < 4) { W = Wl; bias = bl; out = xl; colbase = bn * 128; }
    else        { W = Wr; bias = br; out = xr; colbase = (bn - 4) * 128; }

    const int tid = threadIdx.x;
    const int tm = tid >> 4;        // 0..15
    const int tn = tid & 15;        // 0..15

    float acc[8][8];
#pragma unroll
    for (int i = 0; i < 8; ++i)
#pragma unroll
        for (int j = 0; j < 8; ++j) acc[i][j] = 0.f;

    for (int k0 = 0; k0 < 256; k0 += BK) {
        __syncthreads();
#pragma unroll
        for (int p = 0; p < 2; ++p) {
            int id  = tid + p * 256;
            int row = id >> 2;
            int kc  = (id & 3) << 2;
            float4 v = *(const float4*)&x[(size_t)(bm * BM + row) * 256 + k0 + kc];
            As[kc + 0][row] = v.x; As[kc + 1][row] = v.y;
            As[kc + 2][row] = v.z; As[kc + 3][row] = v.w;
        }
#pragma unroll
        for (int p = 0; p < 2; ++p) {
            int id = tid + p * 256;
            int kk = id >> 5;
            int nf = (id & 31) << 2;
            float4 v = *(const float4*)&W[(size_t)(k0 + kk) * 512 + colbase + nf];
            *(float4*)&Bs[kk][nf] = v;
        }
        __syncthreads();
#pragma unroll
        for (int kk = 0; kk < BK; ++kk) {
            float a[8], b[8];
            *(float4*)&a[0] = *(const float4*)&As[kk][tm * 8];
            *(float4*)&a[4] = *(const float4*)&As[kk][tm * 8 + 4];
            *(float4*)&b[0] = *(const float4*)&Bs[kk][tn * 8];
            *(float4*)&b[4] = *(const float4*)&Bs[kk][tn * 8 + 4];
#pragma unroll
            for (int i = 0; i < 8; ++i)
#pragma unroll
                for (int j = 0; j < 8; ++j) acc[i][j] += a[i] * b[j];
        }
    }

    float bv[8];
    *(float4*)&bv[0] = *(const float4*)&bias[colbase + tn * 8];
    *(float4*)&bv[4] = *(const float4*)&bias[colbase + tn * 8 + 4];
#pragma unroll
    for (int i = 0; i < 8; ++i) {
        int row = bm * BM + tm * 8 + i;
        float4 o0 = make_float4(acc[i][0] + bv[0], acc[i][1] + bv[1],
                                acc[i][2] + bv[2], acc[i][3] + bv[3]);
        float4 o1 = make_float4(acc[i][4] + bv[4], acc[i][5] + bv[5],
                                acc[i][6] + bv[6], acc[i][7] + bv[7]);
        *(float4*)&out[(size_t)row * 512 + colbase + tn * 8]     = o0;
        *(float4*)&out[(size_t)row * 512 + colbase + tn * 8 + 4] = o1;
    }
}

// ---------------------------------------------------------------------------
// Counting sort of edges by dst
// ---------------------------------------------------------------------------
__global__ void k_hist(const int* __restrict__ ei, int* __restrict__ counts)
{
    int e = blockIdx.x * 256 + threadIdx.x;
    if (e < N_EDGES) atomicAdd(&counts[ei[N_EDGES + e]], 1);
}

__global__ __launch_bounds__(1024) void k_scan(
    const int* __restrict__ counts, int* __restrict__ offsets, int* __restrict__ cursors)
{
    __shared__ int part[1024];
    const int tid = threadIdx.x;
    const int base = tid * 32;
    int loc[32];
    int s = 0;
#pragma unroll
    for (int i = 0; i < 32; ++i) { loc[i] = s; s += counts[base + i]; }
    part[tid] = s;
    __syncthreads();
    const int own = s;
    for (int off = 1; off < 1024; off <<= 1) {
        int v = (tid >= off) ? part[tid - off] : 0;
        __syncthreads();
        part[tid] += v;
        __syncthreads();
    }
    const int pre = part[tid] - own;   // exclusive prefix of chunk
#pragma unroll
    for (int i = 0; i < 32; ++i) {
        int o = pre + loc[i];
        offsets[base + i] = o;
        cursors[base + i] = o;
    }
}

__global__ void k_scatter(const int* __restrict__ ei, int* __restrict__ cursors,
                          int* __restrict__ sorted_src, int* __restrict__ sorted_eid)
{
    int e = blockIdx.x * 256 + threadIdx.x;
    if (e >= N_EDGES) return;
    int d = ei[N_EDGES + e];
    int pos = atomicAdd(&cursors[d], 1);
    sorted_src[pos] = ei[e];
    sorted_eid[pos] = e;
}

__global__ void k_gather_ea(const int* __restrict__ sorted_eid,
                            const float* __restrict__ ea, float* __restrict__ sorted_ea)
{
    // 256 threads = 8 edges x 32 cols
    int pos = blockIdx.x * 8 + (threadIdx.x >> 5);
    int col = threadIdx.x & 31;
    int e = sorted_eid[pos];
    sorted_ea[(size_t)pos * 32 + col] = ea[(size_t)e * 32 + col];
}

// ---------------------------------------------------------------------------
// Fused edge kernel, v2:
//   block = 128 threads = 2 independent waves; each wave owns 256 channels
//   (4 consecutive channels per lane). A 16-lane group owns exactly one head
//   (64 channels), so the per-edge alpha reduce is a 4-level shfl butterfly.
//   We lives in 128 registers/lane; ea row addresses are wave-uniform so the
//   compiler emits scalar (SGPR broadcast) loads. No barriers in the edge
//   loop; barriers only for the once-per-dst 512-channel score reduce.
// ---------------------------------------------------------------------------
#define DPW 8

__global__ __launch_bounds__(128) void k_edge_agg(
    const float* __restrict__ xl, const float* __restrict__ xr,
    const float* __restrict__ We, const float* __restrict__ att,
    const float* __restrict__ bias, const float* __restrict__ pw,
    const float* __restrict__ sorted_ea, const int* __restrict__ sorted_src,
    const int* __restrict__ offsets, const int* __restrict__ counts,
    float* __restrict__ h, float* __restrict__ score)
{
    __shared__ float red_s[2];

    const int tid = threadIdx.x;     // 0..127
    const int wv  = tid >> 6;        // wave 0/1
    const int l   = tid & 63;
    const int cbase = wv * 256 + l * 4;   // 4 consecutive channels

    // We fragment in registers: wreg[k] = We[k][cbase..cbase+3]
    float4 wreg[32];
#pragma unroll
    for (int k = 0; k < 32; ++k)
        wreg[k] = *(const float4*)&We[k * 512 + cbase];

    const float4 attv = *(const float4*)&att[cbase];
    const float4 bv   = *(const float4*)&bias[cbase];
    const float4 pwv  = *(const float4*)&pw[cbase];

    // 1/||pw|| once per block
    float nrm = pwv.x*pwv.x + pwv.y*pwv.y + pwv.z*pwv.z + pwv.w*pwv.w;
#pragma unroll
    for (int o = 1; o < 64; o <<= 1) nrm += __shfl_xor(nrm, o);
    if (l == 0) red_s[wv] = nrm;
    __syncthreads();
    const float inv_nrm = 1.0f / sqrtf(red_s[0] + red_s[1]);

    for (int dd = 0; dd < DPW; ++dd) {
        const int d   = blockIdx.x * DPW + dd;
        const int off = offsets[d];
        const int deg = counts[d];
        const float4 xr4 = *(const float4*)&xr[(size_t)d * 512 + cbase];

        float m = -INFINITY, den = 0.f;
        float a0 = 0.f, a1 = 0.f, a2 = 0.f, a3 = 0.f;

        for (int j = 0; j < deg; ++j) {
            const int s = sorted_src[off + j];                        // uniform -> s_load
            const float4 xl4 = *(const float4*)&xl[(size_t)s * 512 + cbase];
            const float* eap = &sorted_ea[(size_t)(off + j) * 32];    // uniform row

            float d0 = 0.f, d1 = 0.f, d2 = 0.f, d3 = 0.f;
#pragma unroll
            for (int k = 0; k < 32; ++k) {
                const float e = eap[k];                               // SGPR broadcast
                d0 += e * wreg[k].x; d1 += e * wreg[k].y;
                d2 += e * wreg[k].z; d3 += e * wreg[k].w;
            }
            float t0 = xl4.x + xr4.x + d0; t0 = t0 > 0.f ? t0 : NEG * t0;
            float t1 = xl4.y + xr4.y + d1; t1 = t1 > 0.f ? t1 : NEG * t1;
            float t2 = xl4.z + xr4.z + d2; t2 = t2 > 0.f ? t2 : NEG * t2;
            float t3 = xl4.w + xr4.w + d3; t3 = t3 > 0.f ? t3 : NEG * t3;

            float p = t0 * attv.x + t1 * attv.y + t2 * attv.z + t3 * attv.w;
#pragma unroll
            for (int o = 1; o < 16; o <<= 1) p += __shfl_xor(p, o);   // head-group sum

            const float mn = fmaxf(m, p);
            const float sc = __expf(m - mn);
            const float pe = __expf(p - mn);
            den = den * sc + pe;
            a0 = a0 * sc + pe * xl4.x;
            a1 = a1 * sc + pe * xl4.y;
            a2 = a2 * sc + pe * xl4.z;
            a3 = a3 * sc + pe * xl4.w;
            m = mn;
        }

        const float r = den > 0.f ? 1.0f / den : 0.f;
        const float h0 = fmaxf(a0 * r + bv.x, 0.f);
        const float h1 = fmaxf(a1 * r + bv.y, 0.f);
        const float h2 = fmaxf(a2 * r + bv.z, 0.f);
        const float h3 = fmaxf(a3 * r + bv.w, 0.f);
        *(float4*)&h[(size_t)d * 512 + cbase] = make_float4(h0, h1, h2, h3);

        float ps = h0 * pwv.x + h1 * pwv.y + h2 * pwv.z + h3 * pwv.w;
#pragma unroll
        for (int o = 1; o < 64; o <<= 1) ps += __shfl_xor(ps, o);     // wave sum
        __syncthreads();                   // protect red_s from previous dst
        if (l == 0) red_s[wv] = ps;
        __syncthreads();
        if (tid == 0) score[d] = tanhf((red_s[0] + red_s[1]) * inv_nrm);
    }
}

// ---------------------------------------------------------------------------
// Per-graph top-K via bitonic sort of packed keys (score desc, idx asc)
// ---------------------------------------------------------------------------
__global__ __launch_bounds__(256) void k_topk(const float* __restrict__ score,
                                              int* __restrict__ sel_idx,
                                              float* __restrict__ sel_val)
{
    __shared__ unsigned long long key[1024];
    const int g = blockIdx.x, tid = threadIdx.x;
    for (int i = tid; i < 1024; i += 256) {
        float s = score[g * 1024 + i];
        unsigned u = __float_as_uint(s);
        u = (u & 0x80000000u) ? ~u : (u | 0x80000000u);   // orderable, ascending
        key[i] = ((unsigned long long)(~u) << 32) | (unsigned)i;  // asc key == desc score
    }
    __syncthreads();
    for (int k = 2; k <= 1024; k <<= 1) {
        for (int j = k >> 1; j > 0; j >>= 1) {
            for (int i = tid; i < 1024; i += 256) {
                int ixj = i ^ j;
                if (ixj > i) {
                    bool up = ((i & k) == 0);
                    unsigned long long a = key[i], b = key[ixj];
                    if ((a > b) == up) { key[i] = b; key[ixj] = a; }
                }
            }
            __syncthreads();
        }
    }
    for (int kk = tid; kk < KSEL; kk += 256) {
        int idx = (int)(key[kk] & 0xFFFFFFFFu);
        sel_idx[g * KSEL + kk] = idx;
        sel_val[g * KSEL + kk] = score[g * 1024 + idx];
    }
}

// ---------------------------------------------------------------------------
// Pool: gmp = max_k(h[idx_k]*val_k), gap = mean_k(...) — k-sliced + merge
// ---------------------------------------------------------------------------
#define KSLICE 103

__global__ __launch_bounds__(256) void k_pool_part(
    const float* __restrict__ h, const int* __restrict__ sel_idx,
    const float* __restrict__ sel_val, float* __restrict__ part)
{
    const int g = blockIdx.x >> 3, sl = blockIdx.x & 7;
    const int kbeg = sl * KSLICE;
    const int kend = min(KSEL, kbeg + KSLICE);
    const int n = kend - kbeg;
    __shared__ float vs[KSLICE];
    __shared__ int   is_[KSLICE];
    const int tid = threadIdx.x;
    if (tid < n) {
        vs[tid]  = sel_val[g * KSEL + kbeg + tid];
        is_[tid] = sel_idx[g * KSEL + kbeg + tid];
    }
    __syncthreads();
    const int c0 = tid, c1 = tid + 256;
    float mx0 = -INFINITY, mx1 = -INFINITY, s0 = 0.f, s1 = 0.f;
    for (int kk = 0; kk < n; ++kk) {
        const float* hp = h + ((size_t)(g * 1024 + is_[kk])) * 512;
        const float v = vs[kk];
        float f0 = hp[c0] * v, f1 = hp[c1] * v;
        mx0 = fmaxf(mx0, f0); s0 += f0;
        mx1 = fmaxf(mx1, f1); s1 += f1;
    }
    const size_t base = ((size_t)blockIdx.x * 2) * 512;
    part[base + c0] = mx0;        part[base + c1] = mx1;
    part[base + 512 + c0] = s0;   part[base + 512 + c1] = s1;
}

__global__ __launch_bounds__(256) void k_pool_merge(
    const float* __restrict__ part, float* __restrict__ out)
{
    const int g = blockIdx.x, tid = threadIdx.x;
    const int c0 = tid, c1 = tid + 256;
    float mx0 = -INFINITY, mx1 = -INFINITY, s0 = 0.f, s1 = 0.f;
    for (int sl = 0; sl < 8; ++sl) {
        const size_t base = ((size_t)(g * 8 + sl) * 2) * 512;
        mx0 = fmaxf(mx0, part[base + c0]); mx1 = fmaxf(mx1, part[base + c1]);
        s0 += part[base + 512 + c0];       s1 += part[base + 512 + c1];
    }
    out[(size_t)g * 1024 + c0] = mx0;
    out[(size_t)g * 1024 + c1] = mx1;
    out[(size_t)g * 1024 + 512 + c0] = s0 * (1.f / KSEL);
    out[(size_t)g * 1024 + 512 + c1] = s1 * (1.f / KSEL);
}

// ---------------------------------------------------------------------------
extern "C" void kernel_launch(void* const* d_in, const int* in_sizes, int n_in,
                              void* d_out, int out_size, void* d_ws, size_t ws_size,
                              hipStream_t stream)
{
    const float* x    = (const float*)d_in[0];
    const float* ea   = (const float*)d_in[1];
    const float* Wl   = (const float*)d_in[2];
    const float* bl   = (const float*)d_in[3];
    const float* Wr   = (const float*)d_in[4];
    const float* br   = (const float*)d_in[5];
    const float* We   = (const float*)d_in[6];
    const float* att  = (const float*)d_in[7];
    const float* bias = (const float*)d_in[8];
    const float* pw   = (const float*)d_in[9];
    const int*   ei   = (const int*)d_in[10];
    float* out = (float*)d_out;

    // workspace layout (floats/ints, 4B each)
    float* xl        = (float*)d_ws;                      // 32768*512
    float* xr        = xl + (size_t)N_NODES * 512;
    float* h         = xr + (size_t)N_NODES * 512;
    float* sorted_ea = h + (size_t)N_NODES * 512;         // E*32
    float* sel_val   = sorted_ea + (size_t)N_EDGES * 32;  // 32*820
    float* part      = sel_val + BGRAPH * KSEL;           // 256*2*512
    float* score     = part + 256 * 2 * 512;              // 32768
    int* counts      = (int*)(score + N_NODES);
    int* offsets     = counts + N_NODES;
    int* cursors     = offsets + N_NODES;
    int* sorted_src  = cursors + N_NODES;                 // E
    int* sorted_eid  = sorted_src + N_EDGES;              // E
    int* sel_idx     = sorted_eid + N_EDGES;              // 32*820

    hipMemsetAsync(counts, 0, (size_t)N_NODES * sizeof(int), stream);

    gemm_xlxr<<<dim3(256, 8), 256, 0, stream>>>(x, Wl, bl, Wr, br, xl, xr);
    k_hist<<<N_EDGES / 256, 256, 0, stream>>>(ei, counts);
    k_scan<<<1, 1024, 0, stream>>>(counts, offsets, cursors);
    k_scatter<<<N_EDGES / 256, 256, 0, stream>>>(ei, cursors, sorted_src, sorted_eid);
    k_gather_ea<<<N_EDGES / 8, 256, 0, stream>>>(sorted_eid, ea, sorted_ea);
    k_edge_agg<<<N_NODES / DPW, 128, 0, stream>>>(xl, xr, We, att, bias, pw,
                                                  sorted_ea, sorted_src, offsets, counts,
                                                  h, score);
    k_topk<<<BGRAPH, 256, 0, stream>>>(score, sel_idx, sel_val);
    k_pool_part<<<BGRAPH * 8, 256, 0, stream>>>(h, sel_idx, sel_val, part);
    k_pool_merge<<<BGRAPH, 256, 0, stream>>>(part, out);
}